// Round 1
// baseline (738.608 us; speedup 1.0000x reference)
//
#include <hip/hip_runtime.h>

typedef __bf16 bf16_t;
typedef __bf16 bf16x8 __attribute__((ext_vector_type(8)));
typedef __bf16 bf16x4 __attribute__((ext_vector_type(4)));
typedef float f32x4 __attribute__((ext_vector_type(4)));

#define GSTR 40   // GEMM LDS row stride (elems): 80B rows -> 16B aligned, 2-way bank aliasing (free)
#define ASTR 72   // attention LDS row stride: 144B rows -> 16B aligned, 2-way aliasing

// ---------------------------------------------------------------------------
// C[M,N] = A[M,K] * B[N,K]^T   (A fp32 or bf16, B fp32; C fp32)
// 128x128 tile per 256-thread block, BK=32, mfma_f32_16x16x32_bf16
// ---------------------------------------------------------------------------
template<bool A_IS_BF16>
__global__ __launch_bounds__(256) void gemm_bt_kernel(
    const void* __restrict__ Av, const float* __restrict__ B,
    float* __restrict__ C, int M, int N, int K)
{
  __shared__ bf16_t As[128 * GSTR];
  __shared__ bf16_t Bs[128 * GSTR];
  const int tid  = threadIdx.x;
  const int lane = tid & 63;
  const int wv   = tid >> 6;
  const int wm   = wv >> 1, wn = wv & 1;
  const int col  = lane & 15, quad = lane >> 4;
  const int bm   = blockIdx.y, bn = blockIdx.x;

  f32x4 acc[4][4] = {};

  const int nkb = K >> 5;
  for (int kb = 0; kb < nkb; ++kb) {
    __syncthreads();
    // ---- stage A tile (128 x 32) ----
    if constexpr (A_IS_BF16) {
      const bf16_t* A = (const bf16_t*)Av;
      int r0 = tid >> 2;
      int c0 = (tid & 3) << 3;
#pragma unroll
      for (int p = 0; p < 2; ++p) {
        int row = r0 + p * 64;
        *(bf16x8*)&As[row * GSTR + c0] =
            *(const bf16x8*)&A[(size_t)(bm * 128 + row) * K + kb * 32 + c0];
      }
    } else {
      const float* A = (const float*)Av;
      int r0 = tid >> 3;
      int c0 = (tid & 7) << 2;
#pragma unroll
      for (int p = 0; p < 4; ++p) {
        int row = r0 + p * 32;
        float4 v = *(const float4*)&A[(size_t)(bm * 128 + row) * K + kb * 32 + c0];
        bf16x4 t;
        t[0] = (bf16_t)v.x; t[1] = (bf16_t)v.y; t[2] = (bf16_t)v.z; t[3] = (bf16_t)v.w;
        *(bf16x4*)&As[row * GSTR + c0] = t;
      }
    }
    // ---- stage B tile (128 x 32, fp32 weights) ----
    {
      int r0 = tid >> 3;
      int c0 = (tid & 7) << 2;
#pragma unroll
      for (int p = 0; p < 4; ++p) {
        int row = r0 + p * 32;
        float4 v = *(const float4*)&B[(size_t)(bn * 128 + row) * K + kb * 32 + c0];
        bf16x4 t;
        t[0] = (bf16_t)v.x; t[1] = (bf16_t)v.y; t[2] = (bf16_t)v.z; t[3] = (bf16_t)v.w;
        *(bf16x4*)&Bs[row * GSTR + c0] = t;
      }
    }
    __syncthreads();

    bf16x8 af[4], bfr[4];
#pragma unroll
    for (int mt = 0; mt < 4; ++mt)
      af[mt] = *(const bf16x8*)&As[(wm * 64 + mt * 16 + col) * GSTR + quad * 8];
#pragma unroll
    for (int nt = 0; nt < 4; ++nt)
      bfr[nt] = *(const bf16x8*)&Bs[(wn * 64 + nt * 16 + col) * GSTR + quad * 8];
#pragma unroll
    for (int mt = 0; mt < 4; ++mt)
#pragma unroll
      for (int nt = 0; nt < 4; ++nt)
        acc[mt][nt] = __builtin_amdgcn_mfma_f32_16x16x32_bf16(af[mt], bfr[nt], acc[mt][nt], 0, 0, 0);
  }

  // epilogue: C/D layout col=lane&15, row=quad*4+reg
#pragma unroll
  for (int mt = 0; mt < 4; ++mt) {
#pragma unroll
    for (int r = 0; r < 4; ++r) {
      int row = bm * 128 + wm * 64 + mt * 16 + quad * 4 + r;
      float* crow = &C[(size_t)row * N + bn * 128 + wn * 64 + col];
#pragma unroll
      for (int nt = 0; nt < 4; ++nt)
        crow[nt * 16] = acc[mt][nt][r];
    }
  }
}

// ---------------------------------------------------------------------------
// Fused RMSNorm + RoPE + layout change.  One wave per (b, s, slot):
// slot 0..31 = Q heads, 32..39 = K heads, 40..47 = V heads (transpose only).
// Q gets SCALE*log2(e) folded in so attention uses exp2 directly.
// ---------------------------------------------------------------------------
__global__ __launch_bounds__(256) void normrope_kernel(
    const float* __restrict__ Qp, const float* __restrict__ Kp, const float* __restrict__ Vp,
    const float* __restrict__ cosT, const float* __restrict__ sinT,
    const float* __restrict__ wq, const float* __restrict__ wk,
    bf16_t* __restrict__ Qn, bf16_t* __restrict__ Kn, bf16_t* __restrict__ Vt)
{
  const int lane = threadIdx.x & 63;
  const int rid  = blockIdx.x * 4 + (threadIdx.x >> 6);
  const int slot = rid % 48;
  const int bs   = rid / 48;
  const int b    = bs >> 11, s = bs & 2047;

  if (slot < 40) {
    const bool isQ = slot < 32;
    const int hh = isQ ? slot : slot - 32;
    float v = isQ ? Qp[(size_t)bs * 2048 + hh * 64 + lane]
                  : Kp[(size_t)bs * 512 + hh * 64 + lane];
    float ss = v * v;
    ss += __shfl_xor(ss, 1, 64);  ss += __shfl_xor(ss, 2, 64);
    ss += __shfl_xor(ss, 4, 64);  ss += __shfl_xor(ss, 8, 64);
    ss += __shfl_xor(ss, 16, 64); ss += __shfl_xor(ss, 32, 64);
    float rr = rsqrtf(ss * (1.0f / 64.0f) + 1e-6f);
    float t  = v * rr * (isQ ? wq[lane] : wk[lane]);
    float rot = __shfl_xor(t, 32, 64);
    rot = (lane < 32) ? -rot : rot;
    float ov = t * cosT[s * 64 + lane] + rot * sinT[s * 64 + lane];
    if (isQ) {
      ov *= 0.125f * 1.4426950408889634f;  // SCALE * log2(e)
      Qn[(((size_t)b * 32 + hh) * 2048 + s) * 64 + lane] = (bf16_t)ov;
    } else {
      Kn[(((size_t)b * 8 + hh) * 2048 + s) * 64 + lane] = (bf16_t)ov;
    }
  } else {
    const int hh = slot - 40;
    float v = Vp[(size_t)bs * 512 + hh * 64 + lane];
    Vt[(((size_t)b * 8 + hh) * 64 + lane) * 2048 + s] = (bf16_t)v;  // transposed [hd][s]
  }
}

// ---------------------------------------------------------------------------
// Flash attention, causal.  Block = (qt, h, b), 256 threads = 4 waves.
// BM=64 q-rows (16 per wave), BN=64 k-cols per iteration, HD=64.
// ---------------------------------------------------------------------------
__global__ __launch_bounds__(256) void attn_kernel(
    const bf16_t* __restrict__ Qn, const bf16_t* __restrict__ Kn,
    const bf16_t* __restrict__ Vt, bf16_t* __restrict__ Ao)
{
  __shared__ bf16_t Qs[64 * ASTR];
  __shared__ bf16_t Ks[64 * ASTR];
  __shared__ bf16_t Vs[64 * ASTR];       // V^T tile: [hd][k]
  __shared__ bf16_t Ps[4 * 16 * ASTR];   // per-wave P scratch

  const int tid = threadIdx.x, lane = tid & 63, w = tid >> 6;
  const int col = lane & 15, quad = lane >> 4;
  const int qt = blockIdx.x, h = blockIdx.y, b = blockIdx.z;
  const int kvh = h >> 2;
  const float NEG_INF = -__builtin_inff();

  const bf16_t* Qb = Qn + (((size_t)(b * 32 + h)) * 2048 + qt * 64) * 64;
  const bf16_t* Kb = Kn + ((size_t)(b * 8 + kvh)) * 2048 * 64;
  const bf16_t* Vb = Vt + ((size_t)(b * 8 + kvh)) * 64 * 2048;

  {  // stage Q tile once
    int r0 = tid >> 3, c0 = (tid & 7) << 3;
#pragma unroll
    for (int p = 0; p < 2; ++p) {
      int row = r0 + p * 32;
      *(bf16x8*)&Qs[row * ASTR + c0] = *(const bf16x8*)&Qb[row * 64 + c0];
    }
  }

  f32x4 o[4] = {};
  float m_i[4] = {NEG_INF, NEG_INF, NEG_INF, NEG_INF};
  float l_i[4] = {};

  for (int j = 0; j <= qt; ++j) {
    __syncthreads();
    {  // stage K tile [s][hd] and V^T tile [hd][s]
      int r0 = tid >> 3, c0 = (tid & 7) << 3;
#pragma unroll
      for (int p = 0; p < 2; ++p) {
        int row = r0 + p * 32;
        *(bf16x8*)&Ks[row * ASTR + c0] = *(const bf16x8*)&Kb[(j * 64 + row) * 64 + c0];
        *(bf16x8*)&Vs[row * ASTR + c0] = *(const bf16x8*)&Vb[(size_t)row * 2048 + j * 64 + c0];
      }
    }
    __syncthreads();

    // S = Q K^T  (already includes scale*log2e via Q)
    f32x4 s[4] = {};
#pragma unroll
    for (int kk = 0; kk < 2; ++kk) {
      bf16x8 a = *(const bf16x8*)&Qs[(w * 16 + col) * ASTR + kk * 32 + quad * 8];
#pragma unroll
      for (int nt = 0; nt < 4; ++nt) {
        bf16x8 kf = *(const bf16x8*)&Ks[(nt * 16 + col) * ASTR + kk * 32 + quad * 8];
        s[nt] = __builtin_amdgcn_mfma_f32_16x16x32_bf16(a, kf, s[nt], 0, 0, 0);
      }
    }

    if (j == qt) {  // diagonal tile: causal mask (k_local > q_local)
#pragma unroll
      for (int nt = 0; nt < 4; ++nt)
#pragma unroll
        for (int r = 0; r < 4; ++r)
          if (nt * 16 + col > w * 16 + quad * 4 + r) s[nt][r] = NEG_INF;
    }

    // online softmax (base-2 domain); rows owned per-quad: row = quad*4+r
    float nm[4], al[4];
#pragma unroll
    for (int r = 0; r < 4; ++r) {
      float mx = fmaxf(fmaxf(s[0][r], s[1][r]), fmaxf(s[2][r], s[3][r]));
      mx = fmaxf(mx, __shfl_xor(mx, 1, 64));
      mx = fmaxf(mx, __shfl_xor(mx, 2, 64));
      mx = fmaxf(mx, __shfl_xor(mx, 4, 64));
      mx = fmaxf(mx, __shfl_xor(mx, 8, 64));
      nm[r] = fmaxf(m_i[r], mx);
      al[r] = exp2f(m_i[r] - nm[r]);   // first iter: exp2(-inf)=0
      m_i[r] = nm[r];
    }
#pragma unroll
    for (int r = 0; r < 4; ++r) {
      float rs = 0.f;
#pragma unroll
      for (int nt = 0; nt < 4; ++nt) {
        float pv = exp2f(s[nt][r] - nm[r]);
        rs += pv;
        Ps[(w * 16 + quad * 4 + r) * ASTR + nt * 16 + col] = (bf16_t)pv;
      }
      rs += __shfl_xor(rs, 1, 64);
      rs += __shfl_xor(rs, 2, 64);
      rs += __shfl_xor(rs, 4, 64);
      rs += __shfl_xor(rs, 8, 64);
      l_i[r] = l_i[r] * al[r] + rs;
#pragma unroll
      for (int nt = 0; nt < 4; ++nt) o[nt][r] *= al[r];
    }
    __syncthreads();  // P write -> A-operand read ordering (cheap, uniform)

    // O += P V   (A-operand from Ps, B-operand from V^T tile)
#pragma unroll
    for (int kk = 0; kk < 2; ++kk) {
      bf16x8 a = *(const bf16x8*)&Ps[(w * 16 + col) * ASTR + kk * 32 + quad * 8];
#pragma unroll
      for (int nt = 0; nt < 4; ++nt) {
        bf16x8 vf = *(const bf16x8*)&Vs[(nt * 16 + col) * ASTR + kk * 32 + quad * 8];
        o[nt] = __builtin_amdgcn_mfma_f32_16x16x32_bf16(a, vf, o[nt], 0, 0, 0);
      }
    }
  }

  // epilogue: divide by l, write token-major bf16 [B*S, H*HD]
#pragma unroll
  for (int r = 0; r < 4; ++r) {
    float inv = 1.0f / l_i[r];
    int row = b * 2048 + qt * 64 + w * 16 + quad * 4 + r;
    bf16_t* orow = &Ao[(size_t)row * 2048 + h * 64 + col];
#pragma unroll
    for (int nt = 0; nt < 4; ++nt)
      orow[nt * 16] = (bf16_t)(o[nt][r] * inv);
  }
}

// ---------------------------------------------------------------------------
extern "C" void kernel_launch(void* const* d_in, const int* in_sizes, int n_in,
                              void* d_out, int out_size, void* d_ws, size_t ws_size,
                              hipStream_t stream)
{
  const float* x    = (const float*)d_in[0];
  // d_in[1] = mask (unused; causal hardcoded)
  const float* cosT = (const float*)d_in[2];
  const float* sinT = (const float*)d_in[3];
  const float* Wq   = (const float*)d_in[4];
  const float* Wk   = (const float*)d_in[5];
  const float* Wv   = (const float*)d_in[6];
  const float* Wo   = (const float*)d_in[7];
  const float* wq   = (const float*)d_in[8];
  const float* wk   = (const float*)d_in[9];
  float* out = (float*)d_out;

  char* ws = (char*)d_ws;
  float*  Qp = (float*)(ws);                   // [4096,2048] fp32   33554432 B
  float*  Kp = (float*)(ws + 33554432);        // [4096, 512] fp32    8388608 B
  float*  Vp = (float*)(ws + 41943040);        // [4096, 512] fp32    8388608 B
  bf16_t* Qn = (bf16_t*)(ws + 50331648);       // [B,H,S,HD]  bf16   16777216 B
  bf16_t* Kn = (bf16_t*)(ws + 67108864);       // [B,KVH,S,HD] bf16   4194304 B
  bf16_t* Vt = (bf16_t*)(ws + 71303168);       // [B,KVH,HD,S] bf16   4194304 B
  bf16_t* Ao = (bf16_t*)(ws + 75497472);       // [4096,2048] bf16   16777216 B
  // total: 92274688 B

  gemm_bt_kernel<false><<<dim3(16, 32), 256, 0, stream>>>(x, Wq, Qp, 4096, 2048, 2048);
  gemm_bt_kernel<false><<<dim3(4, 32),  256, 0, stream>>>(x, Wk, Kp, 4096, 512, 2048);
  gemm_bt_kernel<false><<<dim3(4, 32),  256, 0, stream>>>(x, Wv, Vp, 4096, 512, 2048);
  normrope_kernel<<<49152, 256, 0, stream>>>(Qp, Kp, Vp, cosT, sinT, wq, wk, Qn, Kn, Vt);
  attn_kernel<<<dim3(32, 32, 2), 256, 0, stream>>>(Qn, Kn, Vt, Ao);
  gemm_bt_kernel<true><<<dim3(16, 32), 256, 0, stream>>>(Ao, Wo, out, 4096, 2048, 2048);
}

// Round 2
// 433.289 us; speedup vs baseline: 1.7047x; 1.7047x over previous
//
#include <hip/hip_runtime.h>

typedef __bf16 bf16_t;
typedef __bf16 bf16x8 __attribute__((ext_vector_type(8)));
typedef __bf16 bf16x4 __attribute__((ext_vector_type(4)));
typedef float f32x4 __attribute__((ext_vector_type(4)));
typedef unsigned int u32;

#define AS1 __attribute__((address_space(1)))
#define AS3 __attribute__((address_space(3)))

#define ASTR 72   // attention LDS row stride (elems): 144B rows, 16B aligned

// direct global->LDS, 16B per lane; LDS dest = wave-uniform base + lane*16
__device__ __forceinline__ void g2l16(const bf16_t* g, bf16_t* l) {
  __builtin_amdgcn_global_load_lds((const AS1 u32*)g, (AS3 u32*)l, 16, 0, 0);
}

// ---------------------------------------------------------------------------
// fp32 -> bf16 bulk convert for x, Wq, Wk, Wv, Wo (one dispatch, 1024 elems/blk)
// ---------------------------------------------------------------------------
__global__ __launch_bounds__(256) void cvt5(
    const float* __restrict__ s0, const float* __restrict__ s1,
    const float* __restrict__ s2, const float* __restrict__ s3,
    const float* __restrict__ s4,
    bf16_t* __restrict__ d0, bf16_t* __restrict__ d1, bf16_t* __restrict__ d2,
    bf16_t* __restrict__ d3, bf16_t* __restrict__ d4)
{
  int blk = blockIdx.x;
  const float* s; bf16_t* d; int off;
  if      (blk <  8192) { s = s0; d = d0; off = blk;         }  // x : 8388608
  else if (blk < 12288) { s = s1; d = d1; off = blk -  8192; }  // Wq: 4194304
  else if (blk < 13312) { s = s2; d = d2; off = blk - 12288; }  // Wk: 1048576
  else if (blk < 14336) { s = s3; d = d3; off = blk - 13312; }  // Wv: 1048576
  else                  { s = s4; d = d4; off = blk - 14336; }  // Wo: 4194304
  size_t i = (size_t)off * 1024 + threadIdx.x * 4;
  float4 v = *(const float4*)&s[i];
  bf16x4 t;
  t[0] = (bf16_t)v.x; t[1] = (bf16_t)v.y; t[2] = (bf16_t)v.z; t[3] = (bf16_t)v.w;
  *(bf16x4*)&d[i] = t;
}

// ---------------------------------------------------------------------------
// m97-style GEMM core: C128x128 tile, BK=32, both operands bf16 staged via
// global_load_lds into packed [128][32] LDS.  A,B pre-offset to tile row 0.
// ---------------------------------------------------------------------------
__device__ __forceinline__ void gemm_core(
    const bf16_t* __restrict__ A, const bf16_t* __restrict__ B, int K,
    bf16_t* As, bf16_t* Bs, f32x4 (&acc)[4][4])
{
  const int tid = threadIdx.x, lane = tid & 63, w = tid >> 6;
  const int col = lane & 15, quad = lane >> 4;
  const int wm = w >> 1, wn = w & 1;
  const int lr = lane >> 2, lc = (lane & 3) << 3;  // 4 lanes per 64B row
  const bf16_t* ga = A + (size_t)(w * 16 + lr) * K + lc;
  const bf16_t* gb = B + (size_t)(w * 16 + lr) * K + lc;
  bf16_t* lA = As + w * 16 * 32;  // wave-uniform; lanes land at +lane*8 elems
  bf16_t* lB = Bs + w * 16 * 32;

  const int nkb = K >> 5;
  for (int kb = 0; kb < nkb; ++kb) {
    __syncthreads();
    g2l16(ga + kb * 32,                lA);
    g2l16(ga + kb * 32 + (size_t)64*K, lA + 64 * 32);
    g2l16(gb + kb * 32,                lB);
    g2l16(gb + kb * 32 + (size_t)64*K, lB + 64 * 32);
    __syncthreads();  // compiler emits vmcnt(0) drain here

    bf16x8 af[4], bfr[4];
#pragma unroll
    for (int mt = 0; mt < 4; ++mt)
      af[mt] = *(const bf16x8*)&As[(wm * 64 + mt * 16 + col) * 32 + quad * 8];
#pragma unroll
    for (int nt = 0; nt < 4; ++nt)
      bfr[nt] = *(const bf16x8*)&Bs[(wn * 64 + nt * 16 + col) * 32 + quad * 8];
#pragma unroll
    for (int mt = 0; mt < 4; ++mt)
#pragma unroll
      for (int nt = 0; nt < 4; ++nt)
        acc[mt][nt] = __builtin_amdgcn_mfma_f32_16x16x32_bf16(af[mt], bfr[nt], acc[mt][nt], 0, 0, 0);
  }
}

// merged QKV projection: bn 0..15 -> Q (N=2048), 16..19 -> K, 20..23 -> V (N=512)
__global__ __launch_bounds__(256) void gemm_qkv(
    const bf16_t* __restrict__ xb, const bf16_t* __restrict__ Wqb,
    const bf16_t* __restrict__ Wkb, const bf16_t* __restrict__ Wvb,
    bf16_t* __restrict__ Qp, bf16_t* __restrict__ Kp, bf16_t* __restrict__ Vp)
{
  __shared__ bf16_t As[128 * 32], Bs[128 * 32];
  const int bn = blockIdx.x, bm = blockIdx.y;
  const bf16_t* B; bf16_t* C; int N, cb;
  if      (bn < 16) { B = Wqb + (size_t)bn * 128 * 2048;        C = Qp; N = 2048; cb = bn * 128; }
  else if (bn < 20) { B = Wkb + (size_t)(bn - 16) * 128 * 2048; C = Kp; N = 512;  cb = (bn - 16) * 128; }
  else              { B = Wvb + (size_t)(bn - 20) * 128 * 2048; C = Vp; N = 512;  cb = (bn - 20) * 128; }

  f32x4 acc[4][4] = {};
  gemm_core(xb + (size_t)bm * 128 * 2048, B, 2048, As, Bs, acc);

  const int lane = threadIdx.x & 63, w = threadIdx.x >> 6;
  const int col = lane & 15, quad = lane >> 4, wm = w >> 1, wn = w & 1;
#pragma unroll
  for (int mt = 0; mt < 4; ++mt)
#pragma unroll
    for (int r = 0; r < 4; ++r) {
      int row = bm * 128 + wm * 64 + mt * 16 + quad * 4 + r;
      bf16_t* crow = C + (size_t)row * N + cb + wn * 64 + col;
#pragma unroll
      for (int nt = 0; nt < 4; ++nt)
        crow[nt * 16] = (bf16_t)acc[mt][nt][r];
    }
}

// output projection: A = Ao bf16 [4096,2048], B = Wob bf16, C = out fp32
__global__ __launch_bounds__(256) void gemm_o(
    const bf16_t* __restrict__ Ao, const bf16_t* __restrict__ Wob,
    float* __restrict__ Cf)
{
  __shared__ bf16_t As[128 * 32], Bs[128 * 32];
  const int bn = blockIdx.x, bm = blockIdx.y;
  f32x4 acc[4][4] = {};
  gemm_core(Ao + (size_t)bm * 128 * 2048, Wob + (size_t)bn * 128 * 2048, 2048, As, Bs, acc);

  const int lane = threadIdx.x & 63, w = threadIdx.x >> 6;
  const int col = lane & 15, quad = lane >> 4, wm = w >> 1, wn = w & 1;
#pragma unroll
  for (int mt = 0; mt < 4; ++mt)
#pragma unroll
    for (int r = 0; r < 4; ++r) {
      int row = bm * 128 + wm * 64 + mt * 16 + quad * 4 + r;
      float* crow = Cf + (size_t)row * 2048 + bn * 128 + wn * 64 + col;
#pragma unroll
      for (int nt = 0; nt < 4; ++nt)
        crow[nt * 16] = acc[mt][nt][r];
    }
}

// ---------------------------------------------------------------------------
// RMSNorm + RoPE for Q,K (bf16 in/out).  One wave per (slot, b, s);
// slot 0..31 = Q heads (SCALE*log2e folded in), 32..39 = K heads.
// ---------------------------------------------------------------------------
__global__ __launch_bounds__(256) void normrope(
    const bf16_t* __restrict__ Qp, const bf16_t* __restrict__ Kp,
    const float* __restrict__ cosT, const float* __restrict__ sinT,
    const float* __restrict__ wq, const float* __restrict__ wk,
    bf16_t* __restrict__ Qn, bf16_t* __restrict__ Kn)
{
  const int lane = threadIdx.x & 63;
  const int rid  = blockIdx.x * 4 + (threadIdx.x >> 6);   // 163840 = 40 * 4096
  const int slot = rid >> 12;
  const int bs   = rid & 4095;
  const int b    = bs >> 11, s = bs & 2047;
  const bool isQ = slot < 32;
  const int  hh  = isQ ? slot : slot - 32;

  float v = isQ ? (float)Qp[(size_t)bs * 2048 + hh * 64 + lane]
                : (float)Kp[(size_t)bs * 512  + hh * 64 + lane];
  float ss = v * v;
  ss += __shfl_xor(ss, 1, 64);  ss += __shfl_xor(ss, 2, 64);
  ss += __shfl_xor(ss, 4, 64);  ss += __shfl_xor(ss, 8, 64);
  ss += __shfl_xor(ss, 16, 64); ss += __shfl_xor(ss, 32, 64);
  float rr = rsqrtf(ss * (1.0f / 64.0f) + 1e-6f);
  float t  = v * rr * (isQ ? wq[lane] : wk[lane]);
  float rot = __shfl_xor(t, 32, 64);
  rot = (lane < 32) ? -rot : rot;
  float ov = t * cosT[s * 64 + lane] + rot * sinT[s * 64 + lane];
  if (isQ) {
    ov *= 0.125f * 1.4426950408889634f;  // SCALE * log2(e)
    Qn[(((size_t)b * 32 + hh) * 2048 + s) * 64 + lane] = (bf16_t)ov;
  } else {
    Kn[(((size_t)b * 8 + hh) * 2048 + s) * 64 + lane] = (bf16_t)ov;
  }
}

// ---------------------------------------------------------------------------
// V transpose: Vp [4096, 512] bf16 -> Vt [B,KVH,HD=64,S=2048] bf16.
// Block = (s-tile of 128, kvh, b); LDS 64x(128+8) tile; coalesced both sides.
// ---------------------------------------------------------------------------
__global__ __launch_bounds__(256) void vtrans(
    const bf16_t* __restrict__ Vp, bf16_t* __restrict__ Vt)
{
  __shared__ bf16_t T[64 * 136];
  const int st = blockIdx.x, kvh = blockIdx.y, b = blockIdx.z;
  const int tid = threadIdx.x;
#pragma unroll
  for (int p = 0; p < 4; ++p) {
    int r = p * 32 + (tid >> 3);        // s within tile
    int c = (tid & 7) * 8;              // hd
    bf16x8 v = *(const bf16x8*)&Vp[((size_t)(b * 2048 + st * 128 + r)) * 512 + kvh * 64 + c];
#pragma unroll
    for (int i = 0; i < 8; ++i) T[(c + i) * 136 + r] = v[i];
  }
  __syncthreads();
#pragma unroll
  for (int p = 0; p < 4; ++p) {
    int hd = p * 16 + (tid >> 4);
    int sc = (tid & 15) * 8;
    bf16x8 v = *(const bf16x8*)&T[hd * 136 + sc];
    *(bf16x8*)&Vt[((size_t)((b * 8 + kvh) * 64) + hd) * 2048 + st * 128 + sc] = v;
  }
}

// ---------------------------------------------------------------------------
// Flash attention, causal, no-max softmax (scores bounded: |s|<=~11.6 in
// exp2 domain post-RMSNorm).  l accumulated via ones-column MFMA.
// Block = (qt desc, h, b), 4 waves, BM=64 (16 q-rows/wave), BN=64/iter.
// ---------------------------------------------------------------------------
__global__ __launch_bounds__(256) void attn(
    const bf16_t* __restrict__ Qn, const bf16_t* __restrict__ Kn,
    const bf16_t* __restrict__ Vt, bf16_t* __restrict__ Ao)
{
  __shared__ bf16_t Qs[64 * ASTR];
  __shared__ bf16_t Ks[64 * ASTR];
  __shared__ bf16_t Vs[64 * ASTR];       // V^T tile: [hd][k]
  __shared__ bf16_t Ps[64 * ASTR];       // per-wave P scratch (16 rows each)

  const int tid = threadIdx.x, lane = tid & 63, w = tid >> 6;
  const int col = lane & 15, quad = lane >> 4;
  const int qt = 31 - blockIdx.x;        // longest blocks first
  const int h = blockIdx.y, b = blockIdx.z;
  const int kvh = h >> 2;
  const float NEG_INF = -__builtin_inff();

  const bf16_t* Qb = Qn + (((size_t)(b * 32 + h)) * 2048 + qt * 64) * 64;
  const bf16_t* Kb = Kn + ((size_t)(b * 8 + kvh)) * 2048 * 64;
  const bf16_t* Vb = Vt + ((size_t)(b * 8 + kvh)) * 64 * 2048;

  {  // stage Q tile once
    int r0 = tid >> 3, c0 = (tid & 7) << 3;
#pragma unroll
    for (int p = 0; p < 2; ++p) {
      int row = r0 + p * 32;
      *(bf16x8*)&Qs[row * ASTR + c0] = *(const bf16x8*)&Qb[row * 64 + c0];
    }
  }

  f32x4 o[4] = {};
  f32x4 lacc = {};
  bf16x8 ones;
#pragma unroll
  for (int i = 0; i < 8; ++i) ones[i] = (bf16_t)1.0f;

  for (int j = 0; j <= qt; ++j) {
    __syncthreads();
    {  // stage K [k][hd] and V^T [hd][k]
      int r0 = tid >> 3, c0 = (tid & 7) << 3;
#pragma unroll
      for (int p = 0; p < 2; ++p) {
        int row = r0 + p * 32;
        *(bf16x8*)&Ks[row * ASTR + c0] = *(const bf16x8*)&Kb[(j * 64 + row) * 64 + c0];
        *(bf16x8*)&Vs[row * ASTR + c0] = *(const bf16x8*)&Vb[(size_t)row * 2048 + j * 64 + c0];
      }
    }
    __syncthreads();

    // S = Q K^T (scale*log2e pre-folded into Q)
    f32x4 s[4] = {};
#pragma unroll
    for (int kk = 0; kk < 2; ++kk) {
      bf16x8 a = *(const bf16x8*)&Qs[(w * 16 + col) * ASTR + kk * 32 + quad * 8];
#pragma unroll
      for (int nt = 0; nt < 4; ++nt) {
        bf16x8 kf = *(const bf16x8*)&Ks[(nt * 16 + col) * ASTR + kk * 32 + quad * 8];
        s[nt] = __builtin_amdgcn_mfma_f32_16x16x32_bf16(a, kf, s[nt], 0, 0, 0);
      }
    }

    if (j == qt) {  // diagonal: mask k_local > q_local
#pragma unroll
      for (int nt = 0; nt < 4; ++nt)
#pragma unroll
        for (int r = 0; r < 4; ++r)
          if (nt * 16 + col > w * 16 + quad * 4 + r) s[nt][r] = NEG_INF;
    }

    // p = exp2(s); store to per-wave Ps with XOR-16 swizzle (kills 4-way
    // quad bank aliasing on the b16 writes; reads stay 16B-contiguous)
#pragma unroll
    for (int r = 0; r < 4; ++r) {
      int m = quad * 4 + r;
      int swz = (m & 8) << 1;
      bf16_t* prow = &Ps[(w * 16 + m) * ASTR];
#pragma unroll
      for (int nt = 0; nt < 4; ++nt)
        prow[(nt * 16 + col) ^ swz] = (bf16_t)exp2f(s[nt][r]);
    }
    // Ps is per-wave scratch: same-wave DS ops execute in order; just drain
    // the writes before the dependent reads (no cross-wave barrier needed).
    asm volatile("s_waitcnt lgkmcnt(0)" ::: "memory");

    // O += P V ; l += P · 1 (ones-column MFMA -> rowsum in C layout)
#pragma unroll
    for (int kk = 0; kk < 2; ++kk) {
      int base = kk * 32 + quad * 8;
      bf16x8 a = *(const bf16x8*)&Ps[(w * 16 + col) * ASTR + (base ^ ((col & 8) << 1))];
#pragma unroll
      for (int nt = 0; nt < 4; ++nt) {
        bf16x8 vf = *(const bf16x8*)&Vs[(nt * 16 + col) * ASTR + base];
        o[nt] = __builtin_amdgcn_mfma_f32_16x16x32_bf16(a, vf, o[nt], 0, 0, 0);
      }
      lacc = __builtin_amdgcn_mfma_f32_16x16x32_bf16(a, ones, lacc, 0, 0, 0);
    }
  }

  // epilogue: divide by l, write token-major bf16 [B*S, H*HD]
#pragma unroll
  for (int r = 0; r < 4; ++r) {
    float inv = 1.0f / lacc[r];
    int row = b * 2048 + qt * 64 + w * 16 + quad * 4 + r;
    bf16_t* orow = &Ao[(size_t)row * 2048 + h * 64 + col];
#pragma unroll
    for (int nt = 0; nt < 4; ++nt)
      orow[nt * 16] = (bf16_t)(o[nt][r] * inv);
  }
}

// ---------------------------------------------------------------------------
extern "C" void kernel_launch(void* const* d_in, const int* in_sizes, int n_in,
                              void* d_out, int out_size, void* d_ws, size_t ws_size,
                              hipStream_t stream)
{
  const float* x    = (const float*)d_in[0];
  // d_in[1] = mask (unused; causal hardcoded)
  const float* cosT = (const float*)d_in[2];
  const float* sinT = (const float*)d_in[3];
  const float* Wq   = (const float*)d_in[4];
  const float* Wk   = (const float*)d_in[5];
  const float* Wv   = (const float*)d_in[6];
  const float* Wo   = (const float*)d_in[7];
  const float* wq   = (const float*)d_in[8];
  const float* wk   = (const float*)d_in[9];
  float* out = (float*)d_out;

  char* ws = (char*)d_ws;
  // region            offset       bytes      lifetime
  bf16_t* xb  = (bf16_t*)(ws);                 // 16777216  until gemm_qkv
  bf16_t* Ao  = (bf16_t*)(ws);                 // (reuses xb) attn -> gemm_o
  bf16_t* Wqb = (bf16_t*)(ws + 16777216);      //  8388608  until gemm_qkv
  bf16_t* Vt  = (bf16_t*)(ws + 16777216);      // (reuses Wqb) vtrans -> attn
  bf16_t* Wkb = (bf16_t*)(ws + 25165824);      //  2097152
  bf16_t* Wvb = (bf16_t*)(ws + 27262976);      //  2097152
  bf16_t* Wob = (bf16_t*)(ws + 29360128);      //  8388608  until gemm_o
  bf16_t* Qp  = (bf16_t*)(ws + 37748736);      // 16777216  until normrope
  bf16_t* Kp  = (bf16_t*)(ws + 54525952);      //  4194304  until normrope
  bf16_t* Vp  = (bf16_t*)(ws + 58720256);      //  4194304  until vtrans
  bf16_t* Qn  = (bf16_t*)(ws + 62914560);      // 16777216  until attn
  bf16_t* Kn  = (bf16_t*)(ws + 79691776);      //  4194304  until attn
  // total 83886080 B

  cvt5<<<18432, 256, 0, stream>>>(x, Wq, Wk, Wv, Wo, xb, Wqb, Wkb, Wvb, Wob);
  gemm_qkv<<<dim3(24, 32), 256, 0, stream>>>(xb, Wqb, Wkb, Wvb, Qp, Kp, Vp);
  normrope<<<40960, 256, 0, stream>>>(Qp, Kp, cosT, sinT, wq, wk, Qn, Kn);
  vtrans<<<dim3(16, 8, 2), 256, 0, stream>>>(Vp, Vt);
  attn<<<dim3(32, 32, 2), 256, 0, stream>>>(Qn, Kn, Vt, Ao);
  gemm_o<<<dim3(16, 32), 256, 0, stream>>>(Ao, Wob, out);
}

// Round 3
// 393.926 us; speedup vs baseline: 1.8750x; 1.0999x over previous
//
#include <hip/hip_runtime.h>

typedef __bf16 bf16_t;
typedef __bf16 bf16x8 __attribute__((ext_vector_type(8)));
typedef __bf16 bf16x4 __attribute__((ext_vector_type(4)));
typedef float f32x4 __attribute__((ext_vector_type(4)));
typedef unsigned int u32;

#define AS1 __attribute__((address_space(1)))
#define AS3 __attribute__((address_space(3)))

#define ASTR 72   // attention LDS row stride (elems): 144B rows, 16B aligned

// direct global->LDS, 16B per lane; LDS dest = wave-uniform base + lane*16
__device__ __forceinline__ void g2l16(const bf16_t* g, bf16_t* l) {
  __builtin_amdgcn_global_load_lds((const AS1 u32*)g, (AS3 u32*)l, 16, 0, 0);
}

// ---------------------------------------------------------------------------
// fp32 -> bf16 bulk convert for x, Wq, Wk, Wv, Wo (one dispatch, 1024 elems/blk)
// ---------------------------------------------------------------------------
__global__ __launch_bounds__(256) void cvt5(
    const float* __restrict__ s0, const float* __restrict__ s1,
    const float* __restrict__ s2, const float* __restrict__ s3,
    const float* __restrict__ s4,
    bf16_t* __restrict__ d0, bf16_t* __restrict__ d1, bf16_t* __restrict__ d2,
    bf16_t* __restrict__ d3, bf16_t* __restrict__ d4)
{
  int blk = blockIdx.x;
  const float* s; bf16_t* d; int off;
  if      (blk <  8192) { s = s0; d = d0; off = blk;         }  // x : 8388608
  else if (blk < 12288) { s = s1; d = d1; off = blk -  8192; }  // Wq: 4194304
  else if (blk < 13312) { s = s2; d = d2; off = blk - 12288; }  // Wk: 1048576
  else if (blk < 14336) { s = s3; d = d3; off = blk - 13312; }  // Wv: 1048576
  else                  { s = s4; d = d4; off = blk - 14336; }  // Wo: 4194304
  size_t i = (size_t)off * 1024 + threadIdx.x * 4;
  float4 v = *(const float4*)&s[i];
  bf16x4 t;
  t[0] = (bf16_t)v.x; t[1] = (bf16_t)v.y; t[2] = (bf16_t)v.z; t[3] = (bf16_t)v.w;
  *(bf16x4*)&d[i] = t;
}

// ---------------------------------------------------------------------------
// m97-style GEMM core: C128x128 tile, BK=32, both operands bf16 staged via
// global_load_lds into packed [128][32] LDS.  A,B pre-offset to tile row 0.
// ---------------------------------------------------------------------------
__device__ __forceinline__ void gemm_core(
    const bf16_t* __restrict__ A, const bf16_t* __restrict__ B, int K,
    bf16_t* As, bf16_t* Bs, f32x4 (&acc)[4][4])
{
  const int tid = threadIdx.x, lane = tid & 63, w = tid >> 6;
  const int col = lane & 15, quad = lane >> 4;
  const int wm = w >> 1, wn = w & 1;
  const int lr = lane >> 2, lc = (lane & 3) << 3;  // 4 lanes per 64B row
  const bf16_t* ga = A + (size_t)(w * 16 + lr) * K + lc;
  const bf16_t* gb = B + (size_t)(w * 16 + lr) * K + lc;
  bf16_t* lA = As + w * 16 * 32;  // wave-uniform; lanes land at +lane*8 elems
  bf16_t* lB = Bs + w * 16 * 32;

  const int nkb = K >> 5;
  for (int kb = 0; kb < nkb; ++kb) {
    __syncthreads();
    g2l16(ga + kb * 32,                lA);
    g2l16(ga + kb * 32 + (size_t)64*K, lA + 64 * 32);
    g2l16(gb + kb * 32,                lB);
    g2l16(gb + kb * 32 + (size_t)64*K, lB + 64 * 32);
    __syncthreads();  // compiler emits vmcnt(0) drain here

    bf16x8 af[4], bfr[4];
#pragma unroll
    for (int mt = 0; mt < 4; ++mt)
      af[mt] = *(const bf16x8*)&As[(wm * 64 + mt * 16 + col) * 32 + quad * 8];
#pragma unroll
    for (int nt = 0; nt < 4; ++nt)
      bfr[nt] = *(const bf16x8*)&Bs[(wn * 64 + nt * 16 + col) * 32 + quad * 8];
#pragma unroll
    for (int mt = 0; mt < 4; ++mt)
#pragma unroll
      for (int nt = 0; nt < 4; ++nt)
        acc[mt][nt] = __builtin_amdgcn_mfma_f32_16x16x32_bf16(af[mt], bfr[nt], acc[mt][nt], 0, 0, 0);
  }
}

// merged QKV projection: bn 0..15 -> Q (N=2048), 16..19 -> K, 20..23 -> V (N=512)
__global__ __launch_bounds__(256) void gemm_qkv(
    const bf16_t* __restrict__ xb, const bf16_t* __restrict__ Wqb,
    const bf16_t* __restrict__ Wkb, const bf16_t* __restrict__ Wvb,
    bf16_t* __restrict__ Qp, bf16_t* __restrict__ Kp, bf16_t* __restrict__ Vp)
{
  __shared__ bf16_t As[128 * 32], Bs[128 * 32];
  const int bn = blockIdx.x, bm = blockIdx.y;
  const bf16_t* B; bf16_t* C; int N, cb;
  if      (bn < 16) { B = Wqb + (size_t)bn * 128 * 2048;        C = Qp; N = 2048; cb = bn * 128; }
  else if (bn < 20) { B = Wkb + (size_t)(bn - 16) * 128 * 2048; C = Kp; N = 512;  cb = (bn - 16) * 128; }
  else              { B = Wvb + (size_t)(bn - 20) * 128 * 2048; C = Vp; N = 512;  cb = (bn - 20) * 128; }

  f32x4 acc[4][4] = {};
  gemm_core(xb + (size_t)bm * 128 * 2048, B, 2048, As, Bs, acc);

  const int lane = threadIdx.x & 63, w = threadIdx.x >> 6;
  const int col = lane & 15, quad = lane >> 4, wm = w >> 1, wn = w & 1;
#pragma unroll
  for (int mt = 0; mt < 4; ++mt)
#pragma unroll
    for (int r = 0; r < 4; ++r) {
      int row = bm * 128 + wm * 64 + mt * 16 + quad * 4 + r;
      bf16_t* crow = C + (size_t)row * N + cb + wn * 64 + col;
#pragma unroll
      for (int nt = 0; nt < 4; ++nt)
        crow[nt * 16] = (bf16_t)acc[mt][nt][r];
    }
}

// output projection: A = Ao bf16 [4096,2048], B = Wob bf16, C = out fp32
__global__ __launch_bounds__(256) void gemm_o(
    const bf16_t* __restrict__ Ao, const bf16_t* __restrict__ Wob,
    float* __restrict__ Cf)
{
  __shared__ bf16_t As[128 * 32], Bs[128 * 32];
  const int bn = blockIdx.x, bm = blockIdx.y;
  f32x4 acc[4][4] = {};
  gemm_core(Ao + (size_t)bm * 128 * 2048, Wob + (size_t)bn * 128 * 2048, 2048, As, Bs, acc);

  const int lane = threadIdx.x & 63, w = threadIdx.x >> 6;
  const int col = lane & 15, quad = lane >> 4, wm = w >> 1, wn = w & 1;
#pragma unroll
  for (int mt = 0; mt < 4; ++mt)
#pragma unroll
    for (int r = 0; r < 4; ++r) {
      int row = bm * 128 + wm * 64 + mt * 16 + quad * 4 + r;
      float* crow = Cf + (size_t)row * 2048 + bn * 128 + wn * 64 + col;
#pragma unroll
      for (int nt = 0; nt < 4; ++nt)
        crow[nt * 16] = acc[mt][nt][r];
    }
}

// ---------------------------------------------------------------------------
// RMSNorm + RoPE for Q,K (bf16 in/out).  One wave per (slot, b, s);
// slot 0..31 = Q heads (SCALE*log2e folded in), 32..39 = K heads.
// ---------------------------------------------------------------------------
__global__ __launch_bounds__(256) void normrope(
    const bf16_t* __restrict__ Qp, const bf16_t* __restrict__ Kp,
    const float* __restrict__ cosT, const float* __restrict__ sinT,
    const float* __restrict__ wq, const float* __restrict__ wk,
    bf16_t* __restrict__ Qn, bf16_t* __restrict__ Kn)
{
  const int lane = threadIdx.x & 63;
  const int rid  = blockIdx.x * 4 + (threadIdx.x >> 6);   // 163840 = 40 * 4096
  const int slot = rid >> 12;
  const int bs   = rid & 4095;
  const int b    = bs >> 11, s = bs & 2047;
  const bool isQ = slot < 32;
  const int  hh  = isQ ? slot : slot - 32;

  float v = isQ ? (float)Qp[(size_t)bs * 2048 + hh * 64 + lane]
                : (float)Kp[(size_t)bs * 512  + hh * 64 + lane];
  float ss = v * v;
  ss += __shfl_xor(ss, 1, 64);  ss += __shfl_xor(ss, 2, 64);
  ss += __shfl_xor(ss, 4, 64);  ss += __shfl_xor(ss, 8, 64);
  ss += __shfl_xor(ss, 16, 64); ss += __shfl_xor(ss, 32, 64);
  float rr = rsqrtf(ss * (1.0f / 64.0f) + 1e-6f);
  float t  = v * rr * (isQ ? wq[lane] : wk[lane]);
  float rot = __shfl_xor(t, 32, 64);
  rot = (lane < 32) ? -rot : rot;
  float ov = t * cosT[s * 64 + lane] + rot * sinT[s * 64 + lane];
  if (isQ) {
    ov *= 0.125f * 1.4426950408889634f;  // SCALE * log2(e)
    Qn[(((size_t)b * 32 + hh) * 2048 + s) * 64 + lane] = (bf16_t)ov;
  } else {
    Kn[(((size_t)b * 8 + hh) * 2048 + s) * 64 + lane] = (bf16_t)ov;
  }
}

// ---------------------------------------------------------------------------
// V transpose: Vp [4096, 512] bf16 -> Vt [B,KVH,HD=64,S=2048] bf16.
// ---------------------------------------------------------------------------
__global__ __launch_bounds__(256) void vtrans(
    const bf16_t* __restrict__ Vp, bf16_t* __restrict__ Vt)
{
  __shared__ bf16_t T[64 * 136];
  const int st = blockIdx.x, kvh = blockIdx.y, b = blockIdx.z;
  const int tid = threadIdx.x;
#pragma unroll
  for (int p = 0; p < 4; ++p) {
    int r = p * 32 + (tid >> 3);        // s within tile
    int c = (tid & 7) * 8;              // hd
    bf16x8 v = *(const bf16x8*)&Vp[((size_t)(b * 2048 + st * 128 + r)) * 512 + kvh * 64 + c];
#pragma unroll
    for (int i = 0; i < 8; ++i) T[(c + i) * 136 + r] = v[i];
  }
  __syncthreads();
#pragma unroll
  for (int p = 0; p < 4; ++p) {
    int hd = p * 16 + (tid >> 4);
    int sc = (tid & 15) * 8;
    bf16x8 v = *(const bf16x8*)&T[hd * 136 + sc];
    *(bf16x8*)&Vt[((size_t)((b * 8 + kvh) * 64) + hd) * 2048 + st * 128 + sc] = v;
  }
}

// ---------------------------------------------------------------------------
// Flash attention v3, causal, no-max softmax (|s| bounded post-RMSNorm).
// Block = (qt, h, b): BM=128 q-rows, 4 waves x 32 rows; BN=64 k per iter.
// S computed TRANSPOSED (K as A-operand, Q as B-operand) so each lane holds
// 4 consecutive k for one q-row -> P written as b64 (2-way bank alias, free).
// Q fragments live in registers; l via ones-column MFMA.
// ---------------------------------------------------------------------------
__global__ __launch_bounds__(256, 4) void attn(
    const bf16_t* __restrict__ Qn, const bf16_t* __restrict__ Kn,
    const bf16_t* __restrict__ Vt, bf16_t* __restrict__ Ao)
{
  __shared__ bf16_t Ks[64 * ASTR];
  __shared__ bf16_t Vs[64 * ASTR];        // V^T tile: [hd][k]
  __shared__ bf16_t Ps[128 * ASTR];       // per-wave 32 rows

  const int tid = threadIdx.x, lane = tid & 63, w = tid >> 6;
  const int col = lane & 15, quad = lane >> 4;
  const int qt = 15 - blockIdx.x;         // longest blocks first
  const int h = blockIdx.y, b = blockIdx.z;
  const int kvh = h >> 2;

  const bf16_t* Qb = Qn + (((size_t)(b * 32 + h)) * 2048 + qt * 128) * 64;
  const bf16_t* Kb = Kn + ((size_t)(b * 8 + kvh)) * 2048 * 64;
  const bf16_t* Vb = Vt + ((size_t)(b * 8 + kvh)) * 64 * 2048;

  // Q fragments: registers, loaded once.  Qf[mt][kk]
  bf16x8 Qf[2][2];
#pragma unroll
  for (int mt = 0; mt < 2; ++mt)
#pragma unroll
    for (int kk = 0; kk < 2; ++kk)
      Qf[mt][kk] = *(const bf16x8*)&Qb[(w * 32 + mt * 16 + col) * 64 + kk * 32 + quad * 8];

  f32x4 o[2][4] = {};
  f32x4 lacc[2] = {};
  bf16x8 ones;
#pragma unroll
  for (int i = 0; i < 8; ++i) ones[i] = (bf16_t)1.0f;

  const int rowmax = qt * 128 + w * 32 + 31;   // last q-row this wave owns
  const int rowmin = qt * 128 + w * 32;
  const int jmax = 2 * qt + 1;

  for (int j = 0; j <= jmax; ++j) {
    __syncthreads();
    {  // stage K [k][hd] and V^T [hd][k], padded stride (conflict-free frags)
      int r0 = tid >> 3, c0 = (tid & 7) << 3;
#pragma unroll
      for (int p = 0; p < 2; ++p) {
        int row = r0 + p * 32;
        *(bf16x8*)&Ks[row * ASTR + c0] = *(const bf16x8*)&Kb[(j * 64 + row) * 64 + c0];
        *(bf16x8*)&Vs[row * ASTR + c0] = *(const bf16x8*)&Vb[(size_t)row * 2048 + j * 64 + c0];
      }
    }
    __syncthreads();

    if (j * 64 <= rowmax) {                      // wave-uniform: skip if fully masked
      const bool needmask = (j * 64 + 63 > rowmin);
      // S^T tiles: D[k][q] = K·Q^T ; lane holds q=col, k = kt*16+quad*4+r
#pragma unroll
      for (int kt = 0; kt < 4; ++kt) {
        bf16x8 kf0 = *(const bf16x8*)&Ks[(kt * 16 + col) * ASTR + quad * 8];
        bf16x8 kf1 = *(const bf16x8*)&Ks[(kt * 16 + col) * ASTR + 32 + quad * 8];
        f32x4 st0 = {}, st1 = {};
        st0 = __builtin_amdgcn_mfma_f32_16x16x32_bf16(kf0, Qf[0][0], st0, 0, 0, 0);
        st0 = __builtin_amdgcn_mfma_f32_16x16x32_bf16(kf1, Qf[0][1], st0, 0, 0, 0);
        st1 = __builtin_amdgcn_mfma_f32_16x16x32_bf16(kf0, Qf[1][0], st1, 0, 0, 0);
        st1 = __builtin_amdgcn_mfma_f32_16x16x32_bf16(kf1, Qf[1][1], st1, 0, 0, 0);
        const int k0 = j * 64 + kt * 16 + quad * 4;   // global k of r=0
#pragma unroll
        for (int mt = 0; mt < 2; ++mt) {
          f32x4 st = mt ? st1 : st0;
          const int qg = qt * 128 + w * 32 + mt * 16 + col;  // global q row
          bf16x4 pk;
#pragma unroll
          for (int r = 0; r < 4; ++r) {
            float p = exp2f(st[r]);
            if (needmask && (k0 + r > qg)) p = 0.0f;
            pk[r] = (bf16_t)p;
          }
          *(bf16x4*)&Ps[(w * 32 + mt * 16 + col) * ASTR + kt * 16 + quad * 4] = pk;
        }
      }
      // Ps is per-wave scratch; same-wave DS ordering + drain is enough.
      asm volatile("s_waitcnt lgkmcnt(0)" ::: "memory");

      // O += P V ; l += P · 1
#pragma unroll
      for (int kk = 0; kk < 2; ++kk) {
        bf16x8 pa0 = *(const bf16x8*)&Ps[(w * 32 + col) * ASTR + kk * 32 + quad * 8];
        bf16x8 pa1 = *(const bf16x8*)&Ps[(w * 32 + 16 + col) * ASTR + kk * 32 + quad * 8];
        lacc[0] = __builtin_amdgcn_mfma_f32_16x16x32_bf16(pa0, ones, lacc[0], 0, 0, 0);
        lacc[1] = __builtin_amdgcn_mfma_f32_16x16x32_bf16(pa1, ones, lacc[1], 0, 0, 0);
#pragma unroll
        for (int nt = 0; nt < 4; ++nt) {
          bf16x8 vf = *(const bf16x8*)&Vs[(nt * 16 + col) * ASTR + kk * 32 + quad * 8];
          o[0][nt] = __builtin_amdgcn_mfma_f32_16x16x32_bf16(pa0, vf, o[0][nt], 0, 0, 0);
          o[1][nt] = __builtin_amdgcn_mfma_f32_16x16x32_bf16(pa1, vf, o[1][nt], 0, 0, 0);
        }
      }
    }
  }

  // epilogue: divide by l, write token-major bf16 [B*S, H*HD]
#pragma unroll
  for (int mt = 0; mt < 2; ++mt)
#pragma unroll
    for (int r = 0; r < 4; ++r) {
      float inv = 1.0f / lacc[mt][r];
      int row = b * 2048 + qt * 128 + w * 32 + mt * 16 + quad * 4 + r;
      bf16_t* orow = &Ao[(size_t)row * 2048 + h * 64 + col];
#pragma unroll
      for (int nt = 0; nt < 4; ++nt)
        orow[nt * 16] = (bf16_t)(o[mt][nt][r] * inv);
    }
}

// ---------------------------------------------------------------------------
extern "C" void kernel_launch(void* const* d_in, const int* in_sizes, int n_in,
                              void* d_out, int out_size, void* d_ws, size_t ws_size,
                              hipStream_t stream)
{
  const float* x    = (const float*)d_in[0];
  // d_in[1] = mask (unused; causal hardcoded)
  const float* cosT = (const float*)d_in[2];
  const float* sinT = (const float*)d_in[3];
  const float* Wq   = (const float*)d_in[4];
  const float* Wk   = (const float*)d_in[5];
  const float* Wv   = (const float*)d_in[6];
  const float* Wo   = (const float*)d_in[7];
  const float* wq   = (const float*)d_in[8];
  const float* wk   = (const float*)d_in[9];
  float* out = (float*)d_out;

  char* ws = (char*)d_ws;
  bf16_t* xb  = (bf16_t*)(ws);                 // 16777216  until gemm_qkv
  bf16_t* Ao  = (bf16_t*)(ws);                 // (reuses xb) attn -> gemm_o
  bf16_t* Wqb = (bf16_t*)(ws + 16777216);      //  8388608  until gemm_qkv
  bf16_t* Vt  = (bf16_t*)(ws + 16777216);      // (reuses Wqb) vtrans -> attn
  bf16_t* Wkb = (bf16_t*)(ws + 25165824);      //  2097152
  bf16_t* Wvb = (bf16_t*)(ws + 27262976);      //  2097152
  bf16_t* Wob = (bf16_t*)(ws + 29360128);      //  8388608  until gemm_o
  bf16_t* Qp  = (bf16_t*)(ws + 37748736);      // 16777216  until normrope
  bf16_t* Kp  = (bf16_t*)(ws + 54525952);      //  4194304  until normrope
  bf16_t* Vp  = (bf16_t*)(ws + 58720256);      //  4194304  until vtrans
  bf16_t* Qn  = (bf16_t*)(ws + 62914560);      // 16777216  until attn
  bf16_t* Kn  = (bf16_t*)(ws + 79691776);      //  4194304  until attn

  cvt5<<<18432, 256, 0, stream>>>(x, Wq, Wk, Wv, Wo, xb, Wqb, Wkb, Wvb, Wob);
  gemm_qkv<<<dim3(24, 32), 256, 0, stream>>>(xb, Wqb, Wkb, Wvb, Qp, Kp, Vp);
  normrope<<<40960, 256, 0, stream>>>(Qp, Kp, cosT, sinT, wq, wk, Qn, Kn);
  vtrans<<<dim3(16, 8, 2), 256, 0, stream>>>(Vp, Vt);
  attn<<<dim3(16, 32, 2), 256, 0, stream>>>(Qn, Kn, Vt, Ao);
  gemm_o<<<dim3(16, 32), 256, 0, stream>>>(Ao, Wob, out);
}